// Round 20
// baseline (101.775 us; speedup 1.0000x reference)
//
#include <hip/hip_runtime.h>
#include <hip/hip_bf16.h>
#include <cstdint>

// MultiRelationalGraphDiffusion: out = LeakyReLU( sum_k conv_w[k] * (adj_norm^k @ (h@W^T)) + conv_b )
// B=8, N=2048, D=256, K=4.
//
// Round-20 = R16/R19 (96.0-96.3us) with diffuse at BK=256 (8 K-iters instead of 16):
// halves the per-step sync events (vmcnt drain + barrier convoy). Evidence: R7(32 iters)
// -> R12(16 iters) saved ~3.5us/step at near-equal everything else. NBUF=2 (96 KB ->
// 1 blk/CU; R11==R12 proved 1 vs 2 blk/CU neutral), stage-ahead-1, vmcnt(0) at iter top
// (t+1's loads get ~2600cyc compute cover >> 900cyc worst L2/L3 latency -> drain free).
// Ledger: wait(own loads) -> s_barrier (all tile-t frags visible) -> STAGE(t+1 -> other
// buf, last read at compute(t-1), finished by every wave before barrier(t)) -> compute(t).
// Everything else R16-exact (prepW, fused k_pre, frag layouts, epilogue, scales).
// Scales: adjS=256*adj_norm, cS=16*c -> acc=4096*(adj@c); next cS=acc/256; last tap acc/4096.

#define BATCH 8
#define NN    2048
#define DD    256
#define REPS  1e-9f
#define SLOPE 0.2f

typedef __bf16 bf16x8_t __attribute__((ext_vector_type(8)));
typedef float  f32x4_t  __attribute__((ext_vector_type(4)));

__device__ __forceinline__ void gl2lds16(const void* g, void* l) {
    __builtin_amdgcn_global_load_lds(
        (const __attribute__((address_space(1))) unsigned int*)(uintptr_t)g,
        (__attribute__((address_space(3))) unsigned int*)(unsigned int)(uintptr_t)l,
        16, 0, 0);
}

__device__ __forceinline__ unsigned int pk_fp8x4(float a, float b, float c, float d) {
    int lo = __builtin_amdgcn_cvt_pk_fp8_f32(a, b, 0, false);
    return (unsigned int)__builtin_amdgcn_cvt_pk_fp8_f32(c, d, lo, true);
}

__device__ __forceinline__ f32x4_t cvt_f32_fp8x4(unsigned int u) {
    f32x4_t r;
    r[0] = __builtin_amdgcn_cvt_f32_fp8(u, 0);
    r[1] = __builtin_amdgcn_cvt_f32_fp8(u, 1);
    r[2] = __builtin_amdgcn_cvt_f32_fp8(u, 2);
    r[3] = __builtin_amdgcn_cvt_f32_fp8(u, 3);
    return r;
}

__device__ __forceinline__ uint2 q8(f32x4_t a, f32x4_t b, float sc) {
    uint2 r;
    r.x = pk_fp8x4(a[0] * sc, a[1] * sc, a[2] * sc, a[3] * sc);
    r.y = pk_fp8x4(b[0] * sc, b[1] * sc, b[2] * sc, b[3] * sc);
    return r;
}

// c-frag address (verified R10-R19)
__device__ __forceinline__ size_t cfrag_addr(int b, int row0, int col) {
    return ((size_t)(b * 64 + (row0 >> 5)) * 16 + (col >> 4)) * 512
         + ((col & 15) + 16 * ((row0 >> 3) & 3)) * 8 + (row0 & 4);
}

__device__ __forceinline__ void split8(const f32x4_t v0, const f32x4_t v1,
                                       bf16x8_t& hi, bf16x8_t& lo) {
#pragma unroll
    for (int e = 0; e < 4; ++e) {
        float x = v0[e]; __bf16 hh = (__bf16)x; hi[e] = hh; lo[e] = (__bf16)(x - (float)hh);
        float y = v1[e]; __bf16 hy = (__bf16)y; hi[e + 4] = hy; lo[e + 4] = (__bf16)(y - (float)hy);
    }
}

// ================= prepW: W -> Whi/Wlo bf16, B-frag-major (verified R15-R19) =================
__global__ __launch_bounds__(256) void k_prepW(const float* __restrict__ W,
                                               __bf16* __restrict__ Whi,
                                               __bf16* __restrict__ Wlo) {
    const int t = blockIdx.x * 256 + threadIdx.x;   // 8192 threads
    const int o = t >> 5, k0 = (t & 31) * 8;
    f32x4_t v0 = *(const f32x4_t*)(W + (size_t)o * DD + k0);
    f32x4_t v1 = *(const f32x4_t*)(W + (size_t)o * DD + k0 + 4);
    bf16x8_t hi, lo;
    split8(v0, v1, hi, lo);
    const int f  = (k0 >> 5) * 16 + (o >> 4);
    const int il = (o & 15) + 16 * ((k0 >> 3) & 3);
    *(bf16x8_t*)(Whi + (size_t)f * 512 + il * 8) = hi;
    *(bf16x8_t*)(Wlo + (size_t)f * 512 + il * 8) = lo;
}

// ============ fused pre-pass (verified R16/R19): htrans (bid<256) + normadj ============
__global__ __launch_bounds__(1024, 8) void k_pre(const float* __restrict__ h,
                                                 const __bf16* __restrict__ Whi,
                                                 const __bf16* __restrict__ Wlo,
                                                 const float* __restrict__ adj,
                                                 _Float16* __restrict__ t_h,
                                                 unsigned char* __restrict__ c0f,
                                                 unsigned char* __restrict__ afrag) {
    __shared__ __align__(16) unsigned char fr[64 * 520];   // normadj branch only (33 KB)
    const int bid = blockIdx.x;
    const int tid = threadIdx.x;
    const int w = tid >> 6, l = tid & 63;

    if (bid < 256) {
        // ---------- htrans: wave = one 16n x 64o tile, K=256, bf16x3 MFMA ----------
        const int wt = bid * 16 + w;               // 4096 wave-tiles
        const int b  = wt >> 9;                    // 512 tiles per batch
        const int r9 = wt & 511;
        const int n0 = (r9 >> 2) * 16;             // 128 n-tiles
        const int o0 = (r9 & 3) * 64;              // 4 o-tiles
        const int rl = l & 15, kq = l >> 4;

        f32x4_t acc[4];
#pragma unroll
        for (int j = 0; j < 4; ++j) acc[j] = (f32x4_t){0.f, 0.f, 0.f, 0.f};

        for (int ks = 0; ks < 8; ++ks) {
            const int koff = ks * 32 + kq * 8;
            bf16x8_t ah, al;
            {
                const float* ap = h + ((size_t)b * NN + n0 + rl) * DD + koff;
                split8(*(const f32x4_t*)ap, *(const f32x4_t*)(ap + 4), ah, al);
            }
#pragma unroll
            for (int j = 0; j < 4; ++j) {
                const size_t fo = ((size_t)(ks * 16 + (o0 >> 4) + j)) * 512 + l * 8;
                bf16x8_t bh = *(const bf16x8_t*)(Whi + fo);
                bf16x8_t bl = *(const bf16x8_t*)(Wlo + fo);
                acc[j] = __builtin_amdgcn_mfma_f32_16x16x32_bf16(ah, bh, acc[j], 0, 0, 0);
                acc[j] = __builtin_amdgcn_mfma_f32_16x16x32_bf16(al, bh, acc[j], 0, 0, 0);
                acc[j] = __builtin_amdgcn_mfma_f32_16x16x32_bf16(ah, bl, acc[j], 0, 0, 0);
            }
        }

#pragma unroll
        for (int j = 0; j < 4; ++j) {
            const int row0 = n0 + kq * 4;
            const int col  = o0 + j * 16 + rl;
            _Float16* tp = t_h + ((size_t)b * NN + row0) * DD + col;
#pragma unroll
            for (int r2 = 0; r2 < 4; ++r2) tp[r2 * DD] = (_Float16)acc[j][r2];
            *(unsigned int*)(c0f + cfrag_addr(b, row0, col)) =
                pk_fp8x4(16.f * acc[j][0], 16.f * acc[j][1],
                         16.f * acc[j][2], 16.f * acc[j][3]);
        }
        return;
    }

    // ---------- normadj (verified R10-R19): 16 rows/block, frag-major via LDS ----------
    const int n = (bid - 256) * 16 + w;
    const float* src = adj + (size_t)n * NN;
    f32x4_t v[8];
#pragma unroll
    for (int q = 0; q < 4; ++q) {
        v[2 * q]     = *(const f32x4_t*)(src + q * 512 + l * 8);
        v[2 * q + 1] = *(const f32x4_t*)(src + q * 512 + l * 8 + 4);
    }
    float s = 0.f;
#pragma unroll
    for (int j = 0; j < 8; ++j) s += v[j][0] + v[j][1] + v[j][2] + v[j][3];
#pragma unroll
    for (int m = 1; m < 64; m <<= 1) s += __shfl_xor(s, m, 64);
    const float sc = 256.0f / (s + REPS);
#pragma unroll
    for (int q = 0; q < 4; ++q) {
        uint2 u = q8(v[2 * q], v[2 * q + 1], sc);
        *(uint2*)(fr + (16 * q + (l >> 2)) * 520 + w * 8 + (l & 3) * 128) = u;
    }
    __syncthreads();
    unsigned char* dst = afrag + (size_t)(bid - 256) * 64 * 512;
#pragma unroll
    for (int f2 = 0; f2 < 4; ++f2) {
        const int f = w * 4 + f2;
        *(uint2*)(dst + (size_t)f * 512 + l * 8) = *(const uint2*)(fr + f * 520 + l * 8);
    }
}

// ================= diffuse: BK=256, 8 K-iters, NBUF=2, frag-major LDS =================
// tile 64n x 128o, 512 thr / 8 waves (wr 0..3 x wc 0..1), wave = 16n x 64o.
// A buf 16 KB = 32 frags (f = nfl*8 + ksl); B buf 32 KB = 64 frags (ksl*8 + ofl... laid
// ksl*4096 + ofl*512). 96 KB total -> 1 blk/CU (R11==R12: neutral vs 2).
// Staging per wave per tile: A 2 x 1KB (frags wv*4..wv*4+4, contiguous in global),
// B 4 x 1KB (ksl = wv, 8 of-frags contiguous). 6 loads/wave/tile.
template <bool LAST>
__global__ __launch_bounds__(512) void k_diffuse(const unsigned char* __restrict__ afrag,
                                                 const unsigned char* __restrict__ cin,
                                                 unsigned char* __restrict__ cout,
                                                 const unsigned char* __restrict__ c1f,
                                                 const unsigned char* __restrict__ c2f,
                                                 const _Float16* __restrict__ t_h,
                                                 float* __restrict__ out,
                                                 const float* __restrict__ convw,
                                                 const float* __restrict__ convb) {
    __shared__ __align__(16) unsigned char As[2][16384];   // 32 KB
    __shared__ __align__(16) unsigned char Bs[2][32768];   // 64 KB

    const int tid = threadIdx.x;
    const int p = blockIdx.x;
    const int b  = p & 7;               // batch = XCD
    const int oh = (p >> 3) & 1;        // o-halves 8 IDs apart -> same XCD
    const int n0 = (p >> 4) * 64;

    const int lane = tid & 63, wv = tid >> 6;
    const int wr = wv >> 1, wc = wv & 1;
    const int rl = lane & 15, kq = lane >> 4;

    // A staging source: wave wv -> frags f = wv*4 + q (nfl = wv>>1, ksl = (wv&1)*4 + q)
    // global frag = (b*128 + n0/16 + (wv>>1))*64 + t*8 + (wv&1)*4 + q  (4 contiguous)
    const unsigned char* aSrc = afrag
        + ((size_t)(b * 128 + (n0 >> 4) + (wv >> 1)) * 64 + (wv & 1) * 4) * 512 + lane * 16;
    // B staging source: wave wv -> ksl = wv, of-frags oh*8..oh*8+8 (8 contiguous frags)
    const unsigned char* cSrc = cin
        + ((size_t)(b * 64 + wv) * 16 + oh * 8) * 512 + lane * 16;

    f32x4_t acc[4];
#pragma unroll
    for (int j = 0; j < 4; ++j) acc[j] = (f32x4_t){0.f, 0.f, 0.f, 0.f};

#define STAGE(T, BUF)                                                                  \
    {                                                                                  \
        const unsigned char* as = aSrc + (size_t)(T) * 8 * 512;                        \
        gl2lds16(as,        As[BUF] + wv * 2048);                                      \
        gl2lds16(as + 1024, As[BUF] + wv * 2048 + 1024);                               \
        const unsigned char* cs = cSrc + (size_t)(T) * 8 * 16 * 512;                   \
        gl2lds16(cs,        Bs[BUF] + wv * 4096);                                      \
        gl2lds16(cs + 1024, Bs[BUF] + wv * 4096 + 1024);                               \
        gl2lds16(cs + 2048, Bs[BUF] + wv * 4096 + 2048);                               \
        gl2lds16(cs + 3072, Bs[BUF] + wv * 4096 + 3072);                               \
    }

    STAGE(0, 0)   // prologue: tile 0 -> buf 0 (6 loads outstanding)

    for (int t = 0; t < 8; ++t) {
        asm volatile("s_waitcnt vmcnt(0)" ::: "memory");   // own tile-t loads landed
        __builtin_amdgcn_s_barrier();                      // all waves' tile-t frags in LDS
        __builtin_amdgcn_sched_barrier(0);
        if (t < 7)
            STAGE(t + 1, (t + 1) & 1)                      // other buf; last read compute(t-1)
        __builtin_amdgcn_sched_barrier(0);
        const unsigned char* Ac = As[t & 1];
        const unsigned char* Bc = Bs[t & 1];
        __builtin_amdgcn_s_setprio(1);
#pragma unroll
        for (int s = 0; s < 8; ++s) {
            long a = *(const long*)(Ac + (wr * 8 + s) * 512 + lane * 8);
            long bb[4];
#pragma unroll
            for (int j = 0; j < 4; ++j)
                bb[j] = *(const long*)(Bc + s * 4096 + (wc * 4 + j) * 512 + lane * 8);
#pragma unroll
            for (int j = 0; j < 4; ++j)
                acc[j] = __builtin_amdgcn_mfma_f32_16x16x32_fp8_fp8(a, bb[j], acc[j], 0, 0, 0);
        }
        __builtin_amdgcn_s_setprio(0);
    }
#undef STAGE

    // ---- epilogue (R16-exact): D frag col=lane&15, row=(lane>>4)*4+reg ----
#pragma unroll
    for (int j = 0; j < 4; ++j) {
        const int row0 = n0 + wr * 16 + kq * 4;
        const int col  = oh * 128 + wc * 64 + j * 16 + rl;
        if (LAST) {
            const float cw0 = convw[0], cw1 = convw[1], cw2 = convw[2], cw3 = convw[3];
            const float cb  = convb[0];
            const float ru = 1.0f / 16.0f, rf = 1.0f / 4096.0f;
            float* op = out + ((size_t)b * NN + row0) * DD + col;
            const _Float16* tp = t_h + ((size_t)b * NN + row0) * DD + col;
            const size_t sa = cfrag_addr(b, row0, col);
            f32x4_t u1 = cvt_f32_fp8x4(*(const unsigned int*)(c1f + sa));
            f32x4_t u2 = cvt_f32_fp8x4(*(const unsigned int*)(c2f + sa));
#pragma unroll
            for (int r2 = 0; r2 < 4; ++r2) {
                float v = cw0 * (float)tp[r2 * DD] + cw1 * ru * u1[r2] + cw2 * ru * u2[r2]
                        + cw3 * rf * acc[j][r2] + cb;
                op[r2 * DD] = v >= 0.0f ? v : SLOPE * v;
            }
        } else {
            const float rs = 1.0f / 256.0f;   // acc -> 16*c_next
            *(unsigned int*)(cout + cfrag_addr(b, row0, col)) =
                pk_fp8x4(rs * acc[j][0], rs * acc[j][1], rs * acc[j][2], rs * acc[j][3]);
        }
    }
}

extern "C" void kernel_launch(void* const* d_in, const int* in_sizes, int n_in,
                              void* d_out, int out_size, void* d_ws, size_t ws_size,
                              hipStream_t stream) {
    const float* h   = (const float*)d_in[0];
    const float* adj = (const float*)d_in[1];
    const float* W   = (const float*)d_in[2];
    const float* cw  = (const float*)d_in[3];
    const float* cb  = (const float*)d_in[4];
    float* out = (float*)d_out;

    char* ws = (char*)d_ws;
    unsigned char* afrag = (unsigned char*)ws;                        // 32 MB
    unsigned char* c0f   = (unsigned char*)(ws + 33554432);           // 4 MB
    unsigned char* c1f   = (unsigned char*)(ws + 37748736);           // 4 MB
    unsigned char* c2f   = (unsigned char*)(ws + 41943040);           // 4 MB
    _Float16*      t_h   = (_Float16*)(ws + 46137344);                // 8.4 MB
    __bf16*        Whi   = (__bf16*)(ws + 54525952);                  // 128 KB
    __bf16*        Wlo   = (__bf16*)(ws + 54525952 + 131072);         // 128 KB (~54.8 MB)

    k_prepW<<<32, 256, 0, stream>>>(W, Whi, Wlo);
    k_pre<<<256 + BATCH * NN / 16, 1024, 0, stream>>>(h, Whi, Wlo, adj, t_h, c0f, afrag);
    k_diffuse<false><<<512, 512, 0, stream>>>(afrag, c0f, c1f, nullptr, nullptr, nullptr, out, cw, cb);
    k_diffuse<false><<<512, 512, 0, stream>>>(afrag, c1f, c2f, nullptr, nullptr, nullptr, out, cw, cb);
    k_diffuse<true ><<<512, 512, 0, stream>>>(afrag, c2f, nullptr, c1f, c2f, t_h, out, cw, cb);
}

// Round 21
// 95.389 us; speedup vs baseline: 1.0670x; 1.0670x over previous
//
#include <hip/hip_runtime.h>
#include <hip/hip_bf16.h>
#include <cstdint>

// MultiRelationalGraphDiffusion: out = LeakyReLU( sum_k conv_w[k] * (adj_norm^k @ (h@W^T)) + conv_b )
// B=8, N=2048, D=256, K=4.
//
// FINAL (= R16, best measured 96.0/96.3us; R20's BK=256 regressed to 101.8 -> reverted).
// Converged structure after 20 rounds:
//  - k_prepW: W -> Whi/Wlo bf16 (bf16x3 split), B-frag-major.
//  - k_pre (launch_bounds(1024,8) => <=64 VGPR so normadj keeps 8 waves/SIMD):
//    bid<256 -> LDS-free htrans (wave = 16n x 64o, acc[4], operands direct from
//    h + L2-resident Whi/Wlo); bid>=256 -> normadj (fused rowsum + fp8 x256 quantize,
//    frag-major via LDS transpose). htrans hides under normadj's HBM stream.
//  - k_diffuse x3: 64n x 128o, BK=128 (16 iters), frag-major LDS (conflict-free 512B
//    frag reads), NBUF=3, stage-ahead-2, counted vmcnt(3), batch-per-XCD (b=p&7,
//    c-chain + adjq slice L2-local), o-halves 8 IDs apart, setprio(1) on MFMA.
// Explored-and-rejected: BK 64/256, NBUF 2/4/6, 32x32x16 shape, LDS-free diffuse,
// barrier-free wave-blocks, grid.sync merge (135us/sync!), big-LDS fusion (occupancy),
// register-heavy fusion (VGPR cliff). absmax 0.0078 (threshold 0.0289).
// Scales: adjS=256*adj_norm, cS=16*c -> acc=4096*(adj@c); next cS=acc/256; last tap acc/4096.

#define BATCH 8
#define NN    2048
#define DD    256
#define REPS  1e-9f
#define SLOPE 0.2f

typedef __bf16 bf16x8_t __attribute__((ext_vector_type(8)));
typedef float  f32x4_t  __attribute__((ext_vector_type(4)));

__device__ __forceinline__ void gl2lds16(const void* g, void* l) {
    __builtin_amdgcn_global_load_lds(
        (const __attribute__((address_space(1))) unsigned int*)(uintptr_t)g,
        (__attribute__((address_space(3))) unsigned int*)(unsigned int)(uintptr_t)l,
        16, 0, 0);
}

__device__ __forceinline__ unsigned int pk_fp8x4(float a, float b, float c, float d) {
    int lo = __builtin_amdgcn_cvt_pk_fp8_f32(a, b, 0, false);
    return (unsigned int)__builtin_amdgcn_cvt_pk_fp8_f32(c, d, lo, true);
}

__device__ __forceinline__ f32x4_t cvt_f32_fp8x4(unsigned int u) {
    f32x4_t r;
    r[0] = __builtin_amdgcn_cvt_f32_fp8(u, 0);
    r[1] = __builtin_amdgcn_cvt_f32_fp8(u, 1);
    r[2] = __builtin_amdgcn_cvt_f32_fp8(u, 2);
    r[3] = __builtin_amdgcn_cvt_f32_fp8(u, 3);
    return r;
}

__device__ __forceinline__ uint2 q8(f32x4_t a, f32x4_t b, float sc) {
    uint2 r;
    r.x = pk_fp8x4(a[0] * sc, a[1] * sc, a[2] * sc, a[3] * sc);
    r.y = pk_fp8x4(b[0] * sc, b[1] * sc, b[2] * sc, b[3] * sc);
    return r;
}

// c-frag address (verified R10-R19)
__device__ __forceinline__ size_t cfrag_addr(int b, int row0, int col) {
    return ((size_t)(b * 64 + (row0 >> 5)) * 16 + (col >> 4)) * 512
         + ((col & 15) + 16 * ((row0 >> 3) & 3)) * 8 + (row0 & 4);
}

__device__ __forceinline__ void split8(const f32x4_t v0, const f32x4_t v1,
                                       bf16x8_t& hi, bf16x8_t& lo) {
#pragma unroll
    for (int e = 0; e < 4; ++e) {
        float x = v0[e]; __bf16 hh = (__bf16)x; hi[e] = hh; lo[e] = (__bf16)(x - (float)hh);
        float y = v1[e]; __bf16 hy = (__bf16)y; hi[e + 4] = hy; lo[e + 4] = (__bf16)(y - (float)hy);
    }
}

// ================= prepW: W -> Whi/Wlo bf16, B-frag-major =================
__global__ __launch_bounds__(256) void k_prepW(const float* __restrict__ W,
                                               __bf16* __restrict__ Whi,
                                               __bf16* __restrict__ Wlo) {
    const int t = blockIdx.x * 256 + threadIdx.x;   // 8192 threads
    const int o = t >> 5, k0 = (t & 31) * 8;
    f32x4_t v0 = *(const f32x4_t*)(W + (size_t)o * DD + k0);
    f32x4_t v1 = *(const f32x4_t*)(W + (size_t)o * DD + k0 + 4);
    bf16x8_t hi, lo;
    split8(v0, v1, hi, lo);
    const int f  = (k0 >> 5) * 16 + (o >> 4);
    const int il = (o & 15) + 16 * ((k0 >> 3) & 3);
    *(bf16x8_t*)(Whi + (size_t)f * 512 + il * 8) = hi;
    *(bf16x8_t*)(Wlo + (size_t)f * 512 + il * 8) = lo;
}

// ============ fused pre-pass: htrans (bid<256, register-light) + normadj ============
__global__ __launch_bounds__(1024, 8) void k_pre(const float* __restrict__ h,
                                                 const __bf16* __restrict__ Whi,
                                                 const __bf16* __restrict__ Wlo,
                                                 const float* __restrict__ adj,
                                                 _Float16* __restrict__ t_h,
                                                 unsigned char* __restrict__ c0f,
                                                 unsigned char* __restrict__ afrag) {
    __shared__ __align__(16) unsigned char fr[64 * 520];   // normadj branch only (33 KB)
    const int bid = blockIdx.x;
    const int tid = threadIdx.x;
    const int w = tid >> 6, l = tid & 63;

    if (bid < 256) {
        // ---------- htrans: wave = one 16n x 64o tile, K=256, bf16x3 MFMA ----------
        const int wt = bid * 16 + w;               // 4096 wave-tiles
        const int b  = wt >> 9;                    // 512 tiles per batch
        const int r9 = wt & 511;
        const int n0 = (r9 >> 2) * 16;             // 128 n-tiles
        const int o0 = (r9 & 3) * 64;              // 4 o-tiles
        const int rl = l & 15, kq = l >> 4;

        f32x4_t acc[4];
#pragma unroll
        for (int j = 0; j < 4; ++j) acc[j] = (f32x4_t){0.f, 0.f, 0.f, 0.f};

        for (int ks = 0; ks < 8; ++ks) {
            const int koff = ks * 32 + kq * 8;
            bf16x8_t ah, al;
            {
                const float* ap = h + ((size_t)b * NN + n0 + rl) * DD + koff;
                split8(*(const f32x4_t*)ap, *(const f32x4_t*)(ap + 4), ah, al);
            }
#pragma unroll
            for (int j = 0; j < 4; ++j) {
                const size_t fo = ((size_t)(ks * 16 + (o0 >> 4) + j)) * 512 + l * 8;
                bf16x8_t bh = *(const bf16x8_t*)(Whi + fo);
                bf16x8_t bl = *(const bf16x8_t*)(Wlo + fo);
                acc[j] = __builtin_amdgcn_mfma_f32_16x16x32_bf16(ah, bh, acc[j], 0, 0, 0);
                acc[j] = __builtin_amdgcn_mfma_f32_16x16x32_bf16(al, bh, acc[j], 0, 0, 0);
                acc[j] = __builtin_amdgcn_mfma_f32_16x16x32_bf16(ah, bl, acc[j], 0, 0, 0);
            }
        }

#pragma unroll
        for (int j = 0; j < 4; ++j) {
            const int row0 = n0 + kq * 4;
            const int col  = o0 + j * 16 + rl;
            _Float16* tp = t_h + ((size_t)b * NN + row0) * DD + col;
#pragma unroll
            for (int r2 = 0; r2 < 4; ++r2) tp[r2 * DD] = (_Float16)acc[j][r2];
            *(unsigned int*)(c0f + cfrag_addr(b, row0, col)) =
                pk_fp8x4(16.f * acc[j][0], 16.f * acc[j][1],
                         16.f * acc[j][2], 16.f * acc[j][3]);
        }
        return;
    }

    // ---------- normadj: 16 rows/block, frag-major via LDS ----------
    const int n = (bid - 256) * 16 + w;
    const float* src = adj + (size_t)n * NN;
    f32x4_t v[8];
#pragma unroll
    for (int q = 0; q < 4; ++q) {
        v[2 * q]     = *(const f32x4_t*)(src + q * 512 + l * 8);
        v[2 * q + 1] = *(const f32x4_t*)(src + q * 512 + l * 8 + 4);
    }
    float s = 0.f;
#pragma unroll
    for (int j = 0; j < 8; ++j) s += v[j][0] + v[j][1] + v[j][2] + v[j][3];
#pragma unroll
    for (int m = 1; m < 64; m <<= 1) s += __shfl_xor(s, m, 64);
    const float sc = 256.0f / (s + REPS);
#pragma unroll
    for (int q = 0; q < 4; ++q) {
        uint2 u = q8(v[2 * q], v[2 * q + 1], sc);
        *(uint2*)(fr + (16 * q + (l >> 2)) * 520 + w * 8 + (l & 3) * 128) = u;
    }
    __syncthreads();
    unsigned char* dst = afrag + (size_t)(bid - 256) * 64 * 512;
#pragma unroll
    for (int f2 = 0; f2 < 4; ++f2) {
        const int f = w * 4 + f2;
        *(uint2*)(dst + (size_t)f * 512 + l * 8) = *(const uint2*)(fr + f * 520 + l * 8);
    }
}

// ================= diffuse: frag-major LDS, o-split, batch-per-XCD, counted vmcnt =================
// tile 64n x 128o, BK=128, 512 thr / 8 waves (wr 0..3 x wc 0..1), wave = 16 x 64.
// NBUF=3 -> 72 KB -> 2 blocks/CU. 3 loads/wave/tile (1 A + 2 B).
template <bool LAST>
__global__ __launch_bounds__(512) void k_diffuse(const unsigned char* __restrict__ afrag,
                                                 const unsigned char* __restrict__ cin,
                                                 unsigned char* __restrict__ cout,
                                                 const unsigned char* __restrict__ c1f,
                                                 const unsigned char* __restrict__ c2f,
                                                 const _Float16* __restrict__ t_h,
                                                 float* __restrict__ out,
                                                 const float* __restrict__ convw,
                                                 const float* __restrict__ convb) {
    __shared__ __align__(16) unsigned char As[3][8192];    // 24 KB
    __shared__ __align__(16) unsigned char Bs[3][16384];   // 48 KB

    const int tid = threadIdx.x;
    const int p = blockIdx.x;
    const int b  = p & 7;               // batch = XCD
    const int oh = (p >> 3) & 1;        // o-halves 8 IDs apart -> same XCD
    const int n0 = (p >> 4) * 64;

    const int lane = tid & 63, wv = tid >> 6;
    const int wr = wv >> 1, wc = wv & 1;
    const int rl = lane & 15, kq = lane >> 4;

    const unsigned char* aSrc = afrag
        + ((size_t)(b * 128 + (n0 >> 4) + wr) * 64) * 512 + (wv & 1) * 1024 + lane * 16;
    const unsigned char* cSrc = cin
        + ((size_t)(b * 64) * 16 + oh * 8) * 512 + (wv & 1) * 2048 + lane * 16;

    f32x4_t acc[4];
#pragma unroll
    for (int j = 0; j < 4; ++j) acc[j] = (f32x4_t){0.f, 0.f, 0.f, 0.f};

#define STAGE(T, BUF)                                                                  \
    {                                                                                  \
        const int tt = (T) & 15;                                                       \
        gl2lds16(aSrc + (size_t)tt * 2048, As[BUF] + wr * 2048 + (wv & 1) * 1024);     \
        const unsigned char* cs = cSrc + (size_t)(tt * 4 + wr) * 8192;                 \
        gl2lds16(cs, Bs[BUF] + wr * 4096 + (wv & 1) * 2048);                           \
        gl2lds16(cs + 1024, Bs[BUF] + wr * 4096 + (wv & 1) * 2048 + 1024);             \
    }

    STAGE(0, 0)
    STAGE(1, 1)

    int bc = 0, bs = 2;   // compute buf = t%3, stage buf = (t+2)%3
    for (int t = 0; t < 16; ++t) {
        asm volatile("s_waitcnt vmcnt(3)" ::: "memory");   // tile t's 3 loads landed
        __builtin_amdgcn_s_barrier();                      // all waves' tile-t loads landed
        __builtin_amdgcn_sched_barrier(0);
        STAGE(t + 2, bs)                                   // safe: all finished compute(t-1)
        __builtin_amdgcn_sched_barrier(0);
        const unsigned char* Ac = As[bc];
        const unsigned char* Bc = Bs[bc];
        __builtin_amdgcn_s_setprio(1);
#pragma unroll
        for (int s = 0; s < 4; ++s) {
            long a = *(const long*)(Ac + (wr * 4 + s) * 512 + lane * 8);
            long bb[4];
#pragma unroll
            for (int j = 0; j < 4; ++j)
                bb[j] = *(const long*)(Bc + (s * 8 + wc * 4 + j) * 512 + lane * 8);
#pragma unroll
            for (int j = 0; j < 4; ++j)
                acc[j] = __builtin_amdgcn_mfma_f32_16x16x32_fp8_fp8(a, bb[j], acc[j], 0, 0, 0);
        }
        __builtin_amdgcn_s_setprio(0);
        bc = (bc == 2) ? 0 : bc + 1;
        bs = (bs == 2) ? 0 : bs + 1;
    }
#undef STAGE

    // ---- epilogue: D frag col=lane&15, row=(lane>>4)*4+reg ----
#pragma unroll
    for (int j = 0; j < 4; ++j) {
        const int row0 = n0 + wr * 16 + kq * 4;
        const int col  = oh * 128 + wc * 64 + j * 16 + rl;
        if (LAST) {
            const float cw0 = convw[0], cw1 = convw[1], cw2 = convw[2], cw3 = convw[3];
            const float cb  = convb[0];
            const float ru = 1.0f / 16.0f, rf = 1.0f / 4096.0f;
            float* op = out + ((size_t)b * NN + row0) * DD + col;
            const _Float16* tp = t_h + ((size_t)b * NN + row0) * DD + col;
            const size_t sa = cfrag_addr(b, row0, col);
            f32x4_t u1 = cvt_f32_fp8x4(*(const unsigned int*)(c1f + sa));
            f32x4_t u2 = cvt_f32_fp8x4(*(const unsigned int*)(c2f + sa));
#pragma unroll
            for (int r2 = 0; r2 < 4; ++r2) {
                float v = cw0 * (float)tp[r2 * DD] + cw1 * ru * u1[r2] + cw2 * ru * u2[r2]
                        + cw3 * rf * acc[j][r2] + cb;
                op[r2 * DD] = v >= 0.0f ? v : SLOPE * v;
            }
        } else {
            const float rs = 1.0f / 256.0f;   // acc -> 16*c_next
            *(unsigned int*)(cout + cfrag_addr(b, row0, col)) =
                pk_fp8x4(rs * acc[j][0], rs * acc[j][1], rs * acc[j][2], rs * acc[j][3]);
        }
    }
}

extern "C" void kernel_launch(void* const* d_in, const int* in_sizes, int n_in,
                              void* d_out, int out_size, void* d_ws, size_t ws_size,
                              hipStream_t stream) {
    const float* h   = (const float*)d_in[0];
    const float* adj = (const float*)d_in[1];
    const float* W   = (const float*)d_in[2];
    const float* cw  = (const float*)d_in[3];
    const float* cb  = (const float*)d_in[4];
    float* out = (float*)d_out;

    char* ws = (char*)d_ws;
    unsigned char* afrag = (unsigned char*)ws;                        // 32 MB
    unsigned char* c0f   = (unsigned char*)(ws + 33554432);           // 4 MB
    unsigned char* c1f   = (unsigned char*)(ws + 37748736);           // 4 MB
    unsigned char* c2f   = (unsigned char*)(ws + 41943040);           // 4 MB
    _Float16*      t_h   = (_Float16*)(ws + 46137344);                // 8.4 MB
    __bf16*        Whi   = (__bf16*)(ws + 54525952);                  // 128 KB
    __bf16*        Wlo   = (__bf16*)(ws + 54525952 + 131072);         // 128 KB (~54.8 MB)

    k_prepW<<<32, 256, 0, stream>>>(W, Whi, Wlo);
    k_pre<<<256 + BATCH * NN / 16, 1024, 0, stream>>>(h, Whi, Wlo, adj, t_h, c0f, afrag);
    k_diffuse<false><<<512, 512, 0, stream>>>(afrag, c0f, c1f, nullptr, nullptr, nullptr, out, cw, cb);
    k_diffuse<false><<<512, 512, 0, stream>>>(afrag, c1f, c2f, nullptr, nullptr, nullptr, out, cw, cb);
    k_diffuse<true ><<<512, 512, 0, stream>>>(afrag, c2f, nullptr, c1f, c2f, t_h, out, cw, cb);
}